// Round 1
// baseline (985.298 us; speedup 1.0000x reference)
//
#include <hip/hip_runtime.h>

// MultiHeadAttention: B=2, S=2048, E=512, H=8, dh=64.
// Key insight: reference's reshape(b,H,s,dh) WITHOUT transpose means head h of
// batch b is the contiguous [S,64] row-major block at offset (b*8+h)*S*64 of
// the projected [B,S,E] tensor. Output reshape is the inverse of the same
// mapping, so we write contiguous [S,64] blocks per (b,h) as well.
// Scale quirk: 1/sqrt(s_k) = 1/sqrt(2048), NOT 1/sqrt(dh).

#define SEQ 2048
#define EMB 512
#define DH  64
#define NH  8
#define NB  2
#define MROWS (NB*SEQ)   // 4096 rows in the projection GEMMs

// ---------------------------------------------------------------------------
// Projection GEMM: C[m,n] = sum_k A[m,k]*W[n,k] + bias[n]
// A: [4096,512] row-major, W: [512,512] row-major (we need A @ W^T).
// 64x64 C-tile per block, 256 threads as 16x16, each a 4x4 micro-tile, BK=64.
// ---------------------------------------------------------------------------
__global__ __launch_bounds__(256) void proj_kernel(
    const float* __restrict__ q, const float* __restrict__ k, const float* __restrict__ v,
    const float* __restrict__ Wq, const float* __restrict__ bq,
    const float* __restrict__ Wk, const float* __restrict__ bk,
    const float* __restrict__ Wv, const float* __restrict__ bv,
    float* __restrict__ Qp, float* __restrict__ Kp, float* __restrict__ Vp)
{
    const int z = blockIdx.z;
    const float* A    = (z == 0) ? q  : (z == 1) ? k  : v;
    const float* W    = (z == 0) ? Wq : (z == 1) ? Wk : Wv;
    const float* bias = (z == 0) ? bq : (z == 1) ? bk : bv;
    float*       C    = (z == 0) ? Qp : (z == 1) ? Kp : Vp;

    __shared__ float As[64][68];   // +4 pad: keeps 16B alignment for float4, breaks pow2 strides
    __shared__ float Ws[64][68];

    const int tid = threadIdx.x;
    const int tr = tid >> 4;       // 0..15 (m micro-tile)
    const int tj = tid & 15;       // 0..15 (n micro-tile)
    const int nb = blockIdx.x;     // 0..7
    const int mb = blockIdx.y;     // 0..63

    float acc[4][4] = {};

#pragma unroll 1
    for (int kt = 0; kt < EMB / 64; ++kt) {
#pragma unroll
        for (int it = 0; it < 4; ++it) {
            int f4  = tid + it * 256;            // 0..1023 float4 slots
            int row = f4 >> 4;
            int c4  = (f4 & 15) << 2;
            *(float4*)&As[row][c4] =
                *(const float4*)&A[(size_t)(mb * 64 + row) * EMB + kt * 64 + c4];
            *(float4*)&Ws[row][c4] =
                *(const float4*)&W[(size_t)(nb * 64 + row) * EMB + kt * 64 + c4];
        }
        __syncthreads();
#pragma unroll
        for (int k4 = 0; k4 < 16; ++k4) {
            float4 a4[4], w4[4];
#pragma unroll
            for (int i = 0; i < 4; ++i) a4[i] = *(const float4*)&As[4 * tr + i][k4 * 4];
#pragma unroll
            for (int j = 0; j < 4; ++j) w4[j] = *(const float4*)&Ws[4 * tj + j][k4 * 4];
#pragma unroll
            for (int i = 0; i < 4; ++i)
#pragma unroll
                for (int j = 0; j < 4; ++j)
                    acc[i][j] += a4[i].x * w4[j].x + a4[i].y * w4[j].y +
                                 a4[i].z * w4[j].z + a4[i].w * w4[j].w;
        }
        __syncthreads();
    }

    const int n0 = nb * 64 + 4 * tj;
    const float4 b4 = *(const float4*)&bias[n0];
#pragma unroll
    for (int i = 0; i < 4; ++i) {
        int m = mb * 64 + 4 * tr + i;
        float4 o = { acc[i][0] + b4.x, acc[i][1] + b4.y,
                     acc[i][2] + b4.z, acc[i][3] + b4.w };
        *(float4*)&C[(size_t)m * EMB + n0] = o;
    }
}

// ---------------------------------------------------------------------------
// Flash-style attention. One block = 64 Q rows of one (b,h). 256 threads as
// 16x16; score/PV micro-tiles 4x4. Online softmax: per-row m,l kept redundantly
// in all 16 threads of the row-group (width-16 xor-shuffle reductions; a row's
// 16 owners are 16 consecutive, 16-aligned lanes of one wave).
// LDS: Qs + Vs + KPs (K tile reused as P tile after scores) = 52.2 KB
// -> 3 blocks/CU resident.
// ---------------------------------------------------------------------------
__global__ __launch_bounds__(256) void attn_kernel(
    const float* __restrict__ Qp, const float* __restrict__ Kp,
    const float* __restrict__ Vp, const float* __restrict__ mask,
    float* __restrict__ out)
{
    __shared__ float Qs[64][68];
    __shared__ float KPs[64][68];   // K tile during scores, then P tile for PV
    __shared__ float Vs[64][68];

    const int tid = threadIdx.x;
    const int tr = tid >> 4;        // row micro-group 0..15
    const int tj = tid & 15;        // col micro-group 0..15
    const int bh = blockIdx.x;      // 0..15  (b*8+h)
    const int rb = blockIdx.y;      // 0..31  Q row-block

    const size_t hbase = (size_t)bh * SEQ * DH;
    const float* Qh = Qp + hbase;
    const float* Kh = Kp + hbase;
    const float* Vh = Vp + hbase;
    float*       Oh = out + hbase;

    const float scale = 0.02209708691207961f;  // 1/sqrt(2048)

    // Load Q tile once, pre-scaled. Tile is a contiguous 4096-float span.
#pragma unroll
    for (int it = 0; it < 4; ++it) {
        int f4  = tid + it * 256;
        int row = f4 >> 4;
        int c4  = (f4 & 15) << 2;
        float4 qv = *(const float4*)&Qh[(size_t)rb * 64 * DH + f4 * 4];
        qv.x *= scale; qv.y *= scale; qv.z *= scale; qv.w *= scale;
        *(float4*)&Qs[row][c4] = qv;
    }

    float m_i[4], l_i[4];
    float4 Oacc[4];                  // O[4tr+i][4tj .. 4tj+3]
#pragma unroll
    for (int i = 0; i < 4; ++i) {
        m_i[i] = -1e30f; l_i[i] = 0.f;
        Oacc[i] = make_float4(0.f, 0.f, 0.f, 0.f);
    }

    const int grow0 = rb * 64;

#pragma unroll 1
    for (int kt = 0; kt < SEQ / 64; ++kt) {
        __syncthreads();   // prev-iter PV readers done before K/V overwrite (also orders Qs on kt=0)
#pragma unroll
        for (int it = 0; it < 4; ++it) {
            int f4  = tid + it * 256;
            int row = f4 >> 4;
            int c4  = (f4 & 15) << 2;
            *(float4*)&KPs[row][c4] = *(const float4*)&Kh[(size_t)kt * 4096 + f4 * 4];
            *(float4*)&Vs[row][c4]  = *(const float4*)&Vh[(size_t)kt * 4096 + f4 * 4];
        }
        __syncthreads();

        // ---- scores: sacc[i][j] = Qs[4tr+i] . Ks[4tj+j]  (Q pre-scaled)
        float sacc[4][4] = {};
#pragma unroll
        for (int k4 = 0; k4 < 16; ++k4) {
            float4 a4[4], b4[4];
#pragma unroll
            for (int i = 0; i < 4; ++i) a4[i] = *(const float4*)&Qs[4 * tr + i][k4 * 4];
#pragma unroll
            for (int j = 0; j < 4; ++j) b4[j] = *(const float4*)&KPs[4 * tj + j][k4 * 4];
#pragma unroll
            for (int i = 0; i < 4; ++i)
#pragma unroll
                for (int j = 0; j < 4; ++j)
                    sacc[i][j] += a4[i].x * b4[j].x + a4[i].y * b4[j].y +
                                  a4[i].z * b4[j].z + a4[i].w * b4[j].w;
        }

        // ---- additive mask
        const int c0 = kt * 64 + 4 * tj;
#pragma unroll
        for (int i = 0; i < 4; ++i) {
            float4 mk = *(const float4*)&mask[(size_t)(grow0 + 4 * tr + i) * SEQ + c0];
            sacc[i][0] += mk.x; sacc[i][1] += mk.y;
            sacc[i][2] += mk.z; sacc[i][3] += mk.w;
        }

        __syncthreads();   // everyone done reading K tile before P overwrites it

        // ---- online softmax (per row, across the 16 owner lanes)
        float p[4][4];
#pragma unroll
        for (int i = 0; i < 4; ++i) {
            float mx = fmaxf(fmaxf(sacc[i][0], sacc[i][1]),
                             fmaxf(sacc[i][2], sacc[i][3]));
#pragma unroll
            for (int off = 1; off < 16; off <<= 1)
                mx = fmaxf(mx, __shfl_xor(mx, off, 16));
            const float m_new = fmaxf(m_i[i], mx);
            const float alpha = __expf(m_i[i] - m_new);
            p[i][0] = __expf(sacc[i][0] - m_new);
            p[i][1] = __expf(sacc[i][1] - m_new);
            p[i][2] = __expf(sacc[i][2] - m_new);
            p[i][3] = __expf(sacc[i][3] - m_new);
            float rs = p[i][0] + p[i][1] + p[i][2] + p[i][3];
#pragma unroll
            for (int off = 1; off < 16; off <<= 1)
                rs += __shfl_xor(rs, off, 16);
            l_i[i] = l_i[i] * alpha + rs;
            m_i[i] = m_new;
            Oacc[i].x *= alpha; Oacc[i].y *= alpha;
            Oacc[i].z *= alpha; Oacc[i].w *= alpha;
            *(float4*)&KPs[4 * tr + i][4 * tj] =
                make_float4(p[i][0], p[i][1], p[i][2], p[i][3]);
        }
        __syncthreads();

        // ---- PV: Oacc[i][d] += sum_j P[4tr+i][j] * V[j][4tj+d]
#pragma unroll
        for (int j4 = 0; j4 < 16; ++j4) {
            float4 p4[4], v4[4];
#pragma unroll
            for (int i = 0; i < 4; ++i)  p4[i]  = *(const float4*)&KPs[4 * tr + i][j4 * 4];
#pragma unroll
            for (int jj = 0; jj < 4; ++jj) v4[jj] = *(const float4*)&Vs[j4 * 4 + jj][4 * tj];
#pragma unroll
            for (int i = 0; i < 4; ++i) {
                Oacc[i].x += p4[i].x * v4[0].x + p4[i].y * v4[1].x + p4[i].z * v4[2].x + p4[i].w * v4[3].x;
                Oacc[i].y += p4[i].x * v4[0].y + p4[i].y * v4[1].y + p4[i].z * v4[2].y + p4[i].w * v4[3].y;
                Oacc[i].z += p4[i].x * v4[0].z + p4[i].y * v4[1].z + p4[i].z * v4[2].z + p4[i].w * v4[3].z;
                Oacc[i].w += p4[i].x * v4[0].w + p4[i].y * v4[1].w + p4[i].z * v4[2].w + p4[i].w * v4[3].w;
            }
        }
    }

    // ---- epilogue: normalize by l and store (contiguous [S,64] head block)
#pragma unroll
    for (int i = 0; i < 4; ++i) {
        const float inv = 1.0f / l_i[i];
        float4 o = { Oacc[i].x * inv, Oacc[i].y * inv,
                     Oacc[i].z * inv, Oacc[i].w * inv };
        *(float4*)&Oh[(size_t)(grow0 + 4 * tr + i) * DH + 4 * tj] = o;
    }
}

extern "C" void kernel_launch(void* const* d_in, const int* in_sizes, int n_in,
                              void* d_out, int out_size, void* d_ws, size_t ws_size,
                              hipStream_t stream) {
    const float* q    = (const float*)d_in[0];
    const float* k    = (const float*)d_in[1];
    const float* v    = (const float*)d_in[2];
    const float* mask = (const float*)d_in[3];
    const float* Wq   = (const float*)d_in[4];
    const float* bq   = (const float*)d_in[5];
    const float* Wk   = (const float*)d_in[6];
    const float* bk   = (const float*)d_in[7];
    const float* Wv   = (const float*)d_in[8];
    const float* bv   = (const float*)d_in[9];

    float* Qp = (float*)d_ws;                       // [4096, 512]
    float* Kp = Qp + (size_t)MROWS * EMB;           // [4096, 512]
    float* Vp = Kp + (size_t)MROWS * EMB;           // [4096, 512]  total 24 MB

    dim3 pgrid(EMB / 64, MROWS / 64, 3);            // 8 x 64 x 3 = 1536 blocks
    proj_kernel<<<pgrid, 256, 0, stream>>>(q, k, v, Wq, bq, Wk, bk, Wv, bv,
                                           Qp, Kp, Vp);

    dim3 agrid(NB * NH, SEQ / 64);                  // 16 x 32 = 512 blocks
    attn_kernel<<<agrid, 256, 0, stream>>>(Qp, Kp, Vp, mask, (float*)d_out);
}

// Round 3
// 244.256 us; speedup vs baseline: 4.0339x; 4.0339x over previous
//
#include <hip/hip_runtime.h>

// MultiHeadAttention B=2,S=2048,E=512,H=8,dh=64 — bf16 MFMA version.
// Head mapping (VERIFIED by round-1 pass): reference's reshape(b,H,s,dh) is a
// flat reinterpretation, so head h of batch b is the CONTIGUOUS [S,64] span at
// flat offset (b*8+h)*S*64 of the projected [4096][512] tensor (s-major).
// Round-2 bug was indexing heads as column blocks [row*512+h*64] — wrong.
// V is additionally transposed per head (Vt[bh][d][s]) by a small kernel so
// PV MFMA A-fragments are contiguous 16B reads.
// Scores computed transposed (S^T = K*Q^T): softmax reduce = 2 shuffles, mask
// loads are coalesced float4s matching C-layout rows exactly.
// Scale quirk: 1/sqrt(s_k) = 1/sqrt(2048).

#define SEQ 2048
#define EMB 512
#define DH  64
#define MROWS 4096

typedef float  v4f __attribute__((ext_vector_type(4)));
typedef short  v8s __attribute__((ext_vector_type(8)));

static __device__ __forceinline__ unsigned int f2bf(float f) {
    unsigned int u = __float_as_uint(f);
    u += 0x7fffu + ((u >> 16) & 1u);       // RNE
    return u >> 16;
}
static __device__ __forceinline__ unsigned int pack2(float a, float b) {
    return f2bf(a) | (f2bf(b) << 16);
}

// ---------------------------------------------------------------------------
// Projection: C[m][n] = sum_k A[m][k] * W[n][k] + bias[n], bf16 out.
// A [4096][512] fp32, W [512][512] fp32. Block: 128(m) x 64(n), BK=64.
// 4 waves x (32 m-rows as 2 groups of 16). Straight [4096][512] bf16 output.
// ---------------------------------------------------------------------------
__global__ __launch_bounds__(256, 2) void proj_kernel(
    const float* __restrict__ q, const float* __restrict__ k, const float* __restrict__ v,
    const float* __restrict__ Wq, const float* __restrict__ bq,
    const float* __restrict__ Wk, const float* __restrict__ bk,
    const float* __restrict__ Wv, const float* __restrict__ bv,
    unsigned short* __restrict__ Qbf, unsigned short* __restrict__ Kbf,
    unsigned short* __restrict__ Vbf)
{
    __shared__ __align__(16) char smem[27648];   // As 128x144 | Ws 64x144
    char* As = smem;
    char* Ws = smem + 128 * 144;

    const int z = blockIdx.z;
    const float* A    = (z == 0) ? q  : (z == 1) ? k  : v;
    const float* W    = (z == 0) ? Wq : (z == 1) ? Wk : Wv;
    const float* bias = (z == 0) ? bq : (z == 1) ? bk : bv;
    unsigned short* Cg = (z == 0) ? Qbf : (z == 1) ? Kbf : Vbf;

    const int tid  = threadIdx.x;
    const int w    = tid >> 6;
    const int lane = tid & 63;
    const int qd   = lane >> 4;     // quad 0..3
    const int n    = lane & 15;
    const int nb = blockIdx.x;      // 0..7
    const int mb = blockIdx.y;      // 0..31
    const int m0 = mb * 128, n0 = nb * 64;

    const int rA = tid & 127, hA = tid >> 7;   // A: row, half(32 floats)
    const int rW = tid & 63,  qW = tid >> 6;   // W: row, quarter(16 floats)

    float4 areg[8];
    float4 wreg[4];
#pragma unroll
    for (int i = 0; i < 8; ++i)
        areg[i] = *(const float4*)&A[(size_t)(m0 + rA) * EMB + hA * 32 + i * 4];
#pragma unroll
    for (int i = 0; i < 4; ++i)
        wreg[i] = *(const float4*)&W[(size_t)(n0 + rW) * EMB + qW * 16 + i * 4];

    v4f acc[2][4];
#pragma unroll
    for (int g = 0; g < 2; ++g)
#pragma unroll
        for (int cb = 0; cb < 4; ++cb) acc[g][cb] = (v4f)0.f;

#pragma unroll 1
    for (int kt = 0; kt < 8; ++kt) {
        __syncthreads();
#pragma unroll
        for (int i2 = 0; i2 < 4; ++i2) {
            uint4 pk = { pack2(areg[2*i2].x, areg[2*i2].y), pack2(areg[2*i2].z, areg[2*i2].w),
                         pack2(areg[2*i2+1].x, areg[2*i2+1].y), pack2(areg[2*i2+1].z, areg[2*i2+1].w) };
            *(uint4*)&As[rA * 144 + hA * 64 + i2 * 16] = pk;
        }
#pragma unroll
        for (int i2 = 0; i2 < 2; ++i2) {
            uint4 pk = { pack2(wreg[2*i2].x, wreg[2*i2].y), pack2(wreg[2*i2].z, wreg[2*i2].w),
                         pack2(wreg[2*i2+1].x, wreg[2*i2+1].y), pack2(wreg[2*i2+1].z, wreg[2*i2+1].w) };
            *(uint4*)&Ws[rW * 144 + qW * 32 + i2 * 16] = pk;
        }
        __syncthreads();

        if (kt + 1 < 8) {
#pragma unroll
            for (int i = 0; i < 8; ++i)
                areg[i] = *(const float4*)&A[(size_t)(m0 + rA) * EMB + (kt+1) * 64 + hA * 32 + i * 4];
#pragma unroll
            for (int i = 0; i < 4; ++i)
                wreg[i] = *(const float4*)&W[(size_t)(n0 + rW) * EMB + (kt+1) * 64 + qW * 16 + i * 4];
        }

#pragma unroll
        for (int ks = 0; ks < 2; ++ks) {
            v8s af[2];
#pragma unroll
            for (int g = 0; g < 2; ++g)
                af[g] = *(const v8s*)&As[(w * 32 + g * 16 + n) * 144 + ks * 64 + qd * 16];
#pragma unroll
            for (int cb = 0; cb < 4; ++cb) {
                v8s bfr = *(const v8s*)&Ws[(cb * 16 + n) * 144 + ks * 64 + qd * 16];
#pragma unroll
                for (int g = 0; g < 2; ++g)
                    acc[g][cb] = __builtin_amdgcn_mfma_f32_16x16x32_bf16(af[g], bfr, acc[g][cb], 0, 0, 0);
            }
        }
    }

    float bb[4];
#pragma unroll
    for (int cb = 0; cb < 4; ++cb) bb[cb] = bias[n0 + cb * 16 + n];
#pragma unroll
    for (int g = 0; g < 2; ++g)
#pragma unroll
        for (int cb = 0; cb < 4; ++cb)
#pragma unroll
            for (int r = 0; r < 4; ++r) acc[g][cb][r] += bb[cb];

    __syncthreads();
    // bounce: Ct[128 rows][72 shorts], then coalesced uint4 stores
    short* Ct = (short*)smem;
#pragma unroll
    for (int g = 0; g < 2; ++g)
#pragma unroll
        for (int cb = 0; cb < 4; ++cb)
#pragma unroll
            for (int r = 0; r < 4; ++r)
                Ct[(w * 32 + g * 16 + qd * 4 + r) * 72 + cb * 16 + n] =
                    (short)f2bf(acc[g][cb][r]);
    __syncthreads();
    const int r = tid & 127, hf = tid >> 7;
#pragma unroll
    for (int i = 0; i < 4; ++i) {
        uint4 t4 = *(const uint4*)&smem[r * 144 + hf * 64 + i * 16];
        *(uint4*)&Cg[(size_t)(m0 + r) * EMB + n0 + hf * 32 + i * 8] = t4;
    }
}

// ---------------------------------------------------------------------------
// V transpose per head: Vbf head block (contiguous [2048][64] at bh*S*64)
// -> VtG[bh][64][2048]. One block = 128 s-rows of one head. LDS bounce.
// ---------------------------------------------------------------------------
__global__ __launch_bounds__(256) void vtrans_kernel(
    const unsigned short* __restrict__ Vbf, unsigned short* __restrict__ VtG)
{
    __shared__ unsigned short T[64 * 136];   // [d][s_local], pitch 272B
    const int bh = blockIdx.x, st = blockIdx.y;
    const int tid = threadIdx.x;
    const unsigned short* Vh = Vbf + (size_t)bh * (SEQ * DH) + (size_t)st * 128 * DH;
#pragma unroll
    for (int it = 0; it < 4; ++it) {
        int c = tid + it * 256;              // 0..1023 uint4 chunks
        int s_l = c >> 3, ch = c & 7;
        uint4 t4 = *(const uint4*)&Vh[(size_t)s_l * DH + ch * 8];
        const unsigned short* e = (const unsigned short*)&t4;
#pragma unroll
        for (int j = 0; j < 8; ++j)
            T[(ch * 8 + j) * 136 + s_l] = e[j];
    }
    __syncthreads();
    const int d = tid >> 2, sq = tid & 3;
    unsigned short* Od = VtG + (size_t)bh * (DH * SEQ) + (size_t)d * SEQ + st * 128;
#pragma unroll
    for (int i = 0; i < 4; ++i) {
        uint4 t4 = *(const uint4*)&T[d * 136 + sq * 32 + i * 8];
        *(uint4*)&Od[sq * 32 + i * 8] = t4;
    }
}

// ---------------------------------------------------------------------------
// Flash attention, bf16 MFMA, transposed scores.
// Block: 128 q-rows of one (b,h); 4 waves x 32 q-rows (2 groups of 16).
// Bc = 64. S^T = K*Q^T; online softmax in C-layout (qrow = lane&15);
// P -> per-wave LDS; O^T = Vt*P^T; epilogue transposes O via LDS.
// ---------------------------------------------------------------------------
__global__ __launch_bounds__(256, 1) void attn_kernel(
    const unsigned short* __restrict__ Qbf, const unsigned short* __restrict__ Kbf,
    const unsigned short* __restrict__ VtG, const float* __restrict__ mask,
    float* __restrict__ out)
{
    __shared__ __align__(16) char smem[36864];  // Ks 64x144 | Vts 64x144 | Ps 4x(32x144)
    char* Ks  = smem;
    char* Vts = smem + 9216;

    const int tid  = threadIdx.x;
    const int w    = tid >> 6;
    const int lane = tid & 63;
    const int qd   = lane >> 4;
    const int n    = lane & 15;
    char* Ps = smem + 18432 + w * 4608;

    const int bh = blockIdx.x;           // 0..15
    const int rb = blockIdx.y;           // 0..15

    const unsigned short* Qh = Qbf + (size_t)bh * (SEQ * DH);  // contiguous [2048][64]
    const unsigned short* Kh = Kbf + (size_t)bh * (SEQ * DH);
    const unsigned short* Vth = VtG + (size_t)bh * (DH * SEQ); // [64][2048]

    const float scale = 0.02209708691207961f;   // 1/sqrt(2048)

    // Q fragments (registers, whole kernel): Qh[qrow][k]
    v8s qf[2][2];
#pragma unroll
    for (int g = 0; g < 2; ++g) {
        const size_t qrow = (size_t)(rb * 128 + w * 32 + g * 16 + n);
#pragma unroll
        for (int ks = 0; ks < 2; ++ks)
            qf[g][ks] = *(const v8s*)&Qh[qrow * DH + ks * 32 + qd * 8];
    }

    // staging: lane covers K row sr / Vt d-row sr, chunks (w*2+p)
    const int sr = lane;
    uint4 kreg[2], vreg[2];
#pragma unroll
    for (int p = 0; p < 2; ++p) {
        kreg[p] = *(const uint4*)&Kh[(size_t)sr * DH + (w * 2 + p) * 8];
        vreg[p] = *(const uint4*)&Vth[(size_t)sr * SEQ + (w * 2 + p) * 8];
    }

    float m_[2] = { -1e30f, -1e30f }, l_[2] = { 0.f, 0.f };
    v4f oacc[2][4];
#pragma unroll
    for (int g = 0; g < 2; ++g)
#pragma unroll
        for (int cb = 0; cb < 4; ++cb) oacc[g][cb] = (v4f)0.f;

#pragma unroll 1
    for (int kt = 0; kt < SEQ / 64; ++kt) {
        __syncthreads();
#pragma unroll
        for (int p = 0; p < 2; ++p) {
            *(uint4*)&Ks [sr * 144 + (w * 2 + p) * 16] = kreg[p];
            *(uint4*)&Vts[sr * 144 + (w * 2 + p) * 16] = vreg[p];
        }
        __syncthreads();

        if (kt + 1 < SEQ / 64) {   // prefetch next tile during compute
#pragma unroll
            for (int p = 0; p < 2; ++p) {
                kreg[p] = *(const uint4*)&Kh[(size_t)((kt + 1) * 64 + sr) * DH + (w * 2 + p) * 8];
                vreg[p] = *(const uint4*)&Vth[(size_t)sr * SEQ + (kt + 1) * 64 + (w * 2 + p) * 8];
            }
        }

        // mask loads: float4 components == the 4 C-layout rows (s_k = qd*4+r)
        float4 mk[2][4];
#pragma unroll
        for (int g = 0; g < 2; ++g) {
            const size_t mrow = (size_t)(rb * 128 + w * 32 + g * 16 + n);
#pragma unroll
            for (int cb = 0; cb < 4; ++cb)
                mk[g][cb] = *(const float4*)&mask[mrow * SEQ + kt * 64 + cb * 16 + qd * 4];
        }

        // ---- scores: S^T[s_k][qrow]
        v4f sacc[2][4];
#pragma unroll
        for (int g = 0; g < 2; ++g)
#pragma unroll
            for (int cb = 0; cb < 4; ++cb) sacc[g][cb] = (v4f)0.f;
#pragma unroll
        for (int ks = 0; ks < 2; ++ks)
#pragma unroll
            for (int cb = 0; cb < 4; ++cb) {
                v8s kf = *(const v8s*)&Ks[(cb * 16 + n) * 144 + ks * 64 + qd * 16];
#pragma unroll
                for (int g = 0; g < 2; ++g)
                    sacc[g][cb] = __builtin_amdgcn_mfma_f32_16x16x32_bf16(kf, qf[g][ks], sacc[g][cb], 0, 0, 0);
            }

        // ---- online softmax per qgroup (qrow = lane&15 -> per-lane scalars)
#pragma unroll
        for (int g = 0; g < 2; ++g) {
            float sv[4][4];
            float mx = -1e30f;
#pragma unroll
            for (int cb = 0; cb < 4; ++cb)
#pragma unroll
                for (int r = 0; r < 4; ++r) {
                    float s = fmaf(sacc[g][cb][r], scale, ((const float*)&mk[g][cb])[r]);
                    sv[cb][r] = s;
                    mx = fmaxf(mx, s);
                }
            mx = fmaxf(mx, __shfl_xor(mx, 16));
            mx = fmaxf(mx, __shfl_xor(mx, 32));
            const float mnew  = fmaxf(m_[g], mx);
            const float alpha = __expf(m_[g] - mnew);
            float rs = 0.f;
            float pv[4][4];
#pragma unroll
            for (int cb = 0; cb < 4; ++cb)
#pragma unroll
                for (int r = 0; r < 4; ++r) {
                    float e = __expf(sv[cb][r] - mnew);
                    pv[cb][r] = e;
                    rs += e;
                }
            rs += __shfl_xor(rs, 16);
            rs += __shfl_xor(rs, 32);
            l_[g] = l_[g] * alpha + rs;
            m_[g] = mnew;
#pragma unroll
            for (int cb = 0; cb < 4; ++cb) {
#pragma unroll
                for (int r = 0; r < 4; ++r) oacc[g][cb][r] *= alpha;
                uint2 pk = { pack2(pv[cb][0], pv[cb][1]), pack2(pv[cb][2], pv[cb][3]) };
                *(uint2*)&Ps[(g * 16 + n) * 144 + cb * 32 + qd * 8] = pk;  // same-wave RAW
            }
        }

        // ---- PV: O^T[d][qrow] += Vt * P^T
#pragma unroll
        for (int ks = 0; ks < 2; ++ks) {
            v8s pf[2];
#pragma unroll
            for (int g = 0; g < 2; ++g)
                pf[g] = *(const v8s*)&Ps[(g * 16 + n) * 144 + ks * 64 + qd * 16];
#pragma unroll
            for (int cb = 0; cb < 4; ++cb) {
                v8s vf = *(const v8s*)&Vts[(cb * 16 + n) * 144 + ks * 64 + qd * 16];
#pragma unroll
                for (int g = 0; g < 2; ++g)
                    oacc[g][cb] = __builtin_amdgcn_mfma_f32_16x16x32_bf16(vf, pf[g], oacc[g][cb], 0, 0, 0);
            }
        }
    }

    // ---- epilogue: normalize, transpose via LDS, coalesced store
#pragma unroll
    for (int g = 0; g < 2; ++g) {
        const float inv = 1.0f / l_[g];
#pragma unroll
        for (int cb = 0; cb < 4; ++cb)
#pragma unroll
            for (int r = 0; r < 4; ++r) oacc[g][cb][r] *= inv;
    }
    __syncthreads();
    // O_tile[128 qrows][68 floats (272B)], lane's 4 vals are consecutive d
#pragma unroll
    for (int g = 0; g < 2; ++g)
#pragma unroll
        for (int cb = 0; cb < 4; ++cb)
            *(v4f*)&smem[(w * 32 + g * 16 + n) * 272 + cb * 64 + qd * 16] = oacc[g][cb];
    __syncthreads();
    const int r_l = tid >> 1, hf = tid & 1;
    const size_t obase = (size_t)bh * (SEQ * DH) + (size_t)(rb * 128 + r_l) * DH + hf * 32;
#pragma unroll
    for (int i = 0; i < 8; ++i) {
        float4 t4 = *(const float4*)&smem[r_l * 272 + hf * 128 + i * 16];
        *(float4*)&out[obase + i * 4] = t4;
    }
}

extern "C" void kernel_launch(void* const* d_in, const int* in_sizes, int n_in,
                              void* d_out, int out_size, void* d_ws, size_t ws_size,
                              hipStream_t stream) {
    const float* q    = (const float*)d_in[0];
    const float* k    = (const float*)d_in[1];
    const float* v    = (const float*)d_in[2];
    const float* mask = (const float*)d_in[3];
    const float* Wq   = (const float*)d_in[4];
    const float* bq   = (const float*)d_in[5];
    const float* Wk   = (const float*)d_in[6];
    const float* bk   = (const float*)d_in[7];
    const float* Wv   = (const float*)d_in[8];
    const float* bv   = (const float*)d_in[9];

    unsigned short* Qbf = (unsigned short*)d_ws;                   // [4096][512] bf16
    unsigned short* Kbf = Qbf + (size_t)MROWS * EMB;               // [4096][512] bf16
    unsigned short* Vbf = Kbf + (size_t)MROWS * EMB;               // [4096][512] bf16
    unsigned short* VtG = Vbf + (size_t)MROWS * EMB;               // [16][64][2048] bf16

    dim3 pgrid(EMB / 64, MROWS / 128, 3);    // 8 x 32 x 3 = 768 blocks
    proj_kernel<<<pgrid, 256, 0, stream>>>(q, k, v, Wq, bq, Wk, bk, Wv, bv,
                                           Qbf, Kbf, Vbf);

    dim3 tgrid(16, SEQ / 128);               // 16 x 16 = 256 blocks
    vtrans_kernel<<<tgrid, 256, 0, stream>>>(Vbf, VtG);

    dim3 agrid(16, SEQ / 128);               // 16 x 16 = 256 blocks
    attn_kernel<<<agrid, 256, 0, stream>>>(Qbf, Kbf, VtG, mask, (float*)d_out);
}